// Round 4
// baseline (6374.120 us; speedup 1.0000x reference)
//
#include <hip/hip_runtime.h>
#include <hip/hip_bf16.h>

#define BB 128      // batch
#define TT 32       // seq
#define HH 512      // hidden = emb
#define VV 10000    // vocab
#define VPAD 10240  // vocab padded to 128
#define CFEAT 2048  // cnn features
#define MM 4096     // BB*TT

typedef __attribute__((ext_vector_type(4))) float f32x4;
typedef __attribute__((ext_vector_type(8))) short short8v;
typedef __attribute__((ext_vector_type(4))) short short4v;

__device__ __forceinline__ void gload_lds16(const void* g, void* l) {
  __builtin_amdgcn_global_load_lds(
      (const __attribute__((address_space(1))) unsigned int*)g,
      (__attribute__((address_space(3))) unsigned int*)l, 16, 0, 0);
}

__device__ __forceinline__ float fsigmoid(float x) { return 1.0f / (1.0f + __expf(-x)); }
__device__ __forceinline__ float ftanh(float x) {
  x = fminf(15.0f, fmaxf(-15.0f, x));
  float t = __expf(2.0f * x);
  return (t - 1.0f) / (t + 1.0f);
}

// ---------------------------------------------------------------------------
// Transpose fp32 [K][N] (leading dim ldin) -> bf16 [Npad][K], zero-pad n>=Nreal
// grid (Npad/32, K/32), block 256
__global__ __launch_bounds__(256)
void transpose_to_bf16(const float* __restrict__ in, int ldin, int K, int Nreal,
                       __hip_bfloat16* __restrict__ out)
{
  __shared__ float tile[32][33];
  const int tid = threadIdx.x;
  const int tx = tid & 31, ty = tid >> 5;          // ty 0..7
  const int k0 = blockIdx.y * 32;
  const int n0 = blockIdx.x * 32;
#pragma unroll
  for (int i = 0; i < 4; ++i) {
    int k = k0 + ty + i * 8;
    int n = n0 + tx;
    tile[ty + i * 8][tx] = (n < Nreal) ? in[(size_t)k * ldin + n] : 0.0f;
  }
  __syncthreads();
#pragma unroll
  for (int i = 0; i < 4; ++i) {
    int n = n0 + ty + i * 8;
    int k = k0 + tx;
    out[(size_t)n * K + k] = __float2bfloat16(tile[tx][ty + i * 8]);
  }
}

// ---------------------------------------------------------------------------
// h0 = tanh(cnn @ in_W + in_b).  grid (8,16) block 256
__global__ __launch_bounds__(256)
void h0_kernel(const float* __restrict__ cnn, const float* __restrict__ inW,
               const float* __restrict__ inb, float* __restrict__ h0)
{
  __shared__ float xT[8][CFEAT];                   // 64 KB
  const int tid = threadIdx.x;
  const int r0 = blockIdx.y * 8;
  const int j0 = blockIdx.x * 64;
  {
    const float4* src = (const float4*)(cnn + (size_t)r0 * CFEAT);
    float4* dst = (float4*)&xT[0][0];
    for (int i = tid; i < 4096; i += 256) dst[i] = src[i];
  }
  __syncthreads();
  const int jj = tid & 63, rg = tid >> 6;
  const int j = j0 + jj;
  float a0 = 0.0f, a1 = 0.0f;
  for (int k4 = 0; k4 < CFEAT; k4 += 4) {
    f32x4 x0 = *(const f32x4*)&xT[rg * 2 + 0][k4];
    f32x4 x1 = *(const f32x4*)&xT[rg * 2 + 1][k4];
#pragma unroll
    for (int kk = 0; kk < 4; ++kk) {
      float wv = inW[(size_t)(k4 + kk) * HH + j];
      a0 += x0[kk] * wv;
      a1 += x1[kk] * wv;
    }
  }
  const float bb = inb[j];
  const int row0 = r0 + rg * 2;
  h0[(size_t)(row0 + 0) * HH + j] = ftanh(a0 + bb);
  h0[(size_t)(row0 + 1) * HH + j] = ftanh(a1 + bb);
}

// ---------------------------------------------------------------------------
// Gather embedding rows -> bf16 Xe[t*128+b][512].  grid 4096, block 128
__global__ __launch_bounds__(128)
void gather_kernel(const int* __restrict__ xTok, const float* __restrict__ emb,
                   __hip_bfloat16* __restrict__ Xe)
{
  const int r = blockIdx.x;            // t*128 + b
  const int t = r >> 7, b = r & 127;
  const int tok = xTok[b * TT + t];
  float4 v = ((const float4*)(emb + (size_t)tok * HH))[threadIdx.x];
  __hip_bfloat16 o[4] = { __float2bfloat16(v.x), __float2bfloat16(v.y),
                          __float2bfloat16(v.z), __float2bfloat16(v.w) };
  *(short4v*)(Xe + (size_t)r * HH + threadIdx.x * 4) = *(const short4v*)o;
}

// ---------------------------------------------------------------------------
// bf16 MFMA GEMM, C[M][Nreal] = A[M][512] @ BT[Npad][512]^T (+ bias).
// 128x128 tile, BK=32, 4 waves 2x2, global_load_lds w16.
// REMAP: row = t*128+b -> store C[(b*32+t)*Nreal + col]  (logits layout)
template<bool REMAP, bool HASBIAS>
__global__ __launch_bounds__(256)
void mfma_gemm_bt(const __hip_bfloat16* __restrict__ A,
                  const __hip_bfloat16* __restrict__ BT,
                  const float* __restrict__ bias,
                  float* __restrict__ C, int Nreal)
{
  constexpr int K = 512;
  __shared__ __hip_bfloat16 ldsA[128 * 32];
  __shared__ __hip_bfloat16 ldsB[128 * 32];
  const int tid = threadIdx.x;
  const int lane = tid & 63;
  const int w = tid >> 6;
  const long m0 = (long)blockIdx.y * 128;
  const long n0 = (long)blockIdx.x * 128;
  const int wr = (w >> 1) * 64, wc = (w & 1) * 64;
  const int srow = lane >> 2;            // 0..15 within 16-row chunk
  const int skoff = (lane & 3) * 8;      // k element offset
  f32x4 acc[4][4] = {};

  for (int kt = 0; kt < K; kt += 32) {
    __syncthreads();
#pragma unroll
    for (int i = 0; i < 2; ++i) {
      int c = w + i * 4;                 // chunk 0..7 (16 rows each)
      int row = c * 16 + srow;
      gload_lds16(A + (m0 + row) * K + kt + skoff, ldsA + c * 512 + lane * 8);
      gload_lds16(BT + (n0 + row) * K + kt + skoff, ldsB + c * 512 + lane * 8);
    }
    __syncthreads();
    short8v af[4], bfv[4];
#pragma unroll
    for (int m = 0; m < 4; ++m)
      af[m] = *(const short8v*)(ldsA + (wr + m * 16 + (lane & 15)) * 32 + (lane >> 4) * 8);
#pragma unroll
    for (int n = 0; n < 4; ++n)
      bfv[n] = *(const short8v*)(ldsB + (wc + n * 16 + (lane & 15)) * 32 + (lane >> 4) * 8);
#pragma unroll
    for (int m = 0; m < 4; ++m)
#pragma unroll
      for (int n = 0; n < 4; ++n)
        acc[m][n] = __builtin_amdgcn_mfma_f32_16x16x32_bf16(af[m], bfv[n], acc[m][n], 0, 0, 0);
  }

#pragma unroll
  for (int m = 0; m < 4; ++m) {
#pragma unroll
    for (int n = 0; n < 4; ++n) {
      int col = (int)n0 + wc + n * 16 + (lane & 15);
      if (col < Nreal) {
        float bv = 0.0f;
        if constexpr (HASBIAS) bv = bias[col];
#pragma unroll
        for (int q = 0; q < 4; ++q) {
          long row = m0 + wr + m * 16 + (lane >> 4) * 4 + q;
          float v = acc[m][n][q] + bv;
          if (REMAP) {
            long t = row >> 7, b = row & 127;
            C[(b * TT + t) * (long)Nreal + col] = v;
          } else {
            C[row * (long)Nreal + col] = v;
          }
        }
      }
    }
  }
}

// ---------------------------------------------------------------------------
// Persistent GRU scan: 8 WGs x 512 threads; WG g owns batch rows [g*16, g*16+16)
// for ALL 32 timesteps. h0/h1 state fp32 in LDS; recurrent matmuls bf16 MFMA.
// Zero inter-WG communication (batch rows independent; weights shared read-only).
__device__ __forceinline__ void load_af(short8v af[16], const __hip_bfloat16* A,
                                        int cl, int kh)
{
#pragma unroll
  for (int kk = 0; kk < 16; ++kk)
    af[kk] = *(const short8v*)(A + cl * 512 + kk * 32 + kh);
}

__device__ __forceinline__ void mm4(f32x4 acc[4], const short8v af[16],
                                    const __hip_bfloat16* __restrict__ Wb,
                                    int ldk, int col0, int cl, int kh)
{
#pragma unroll
  for (int ct = 0; ct < 4; ++ct) {
    const __hip_bfloat16* bp = Wb + (size_t)(col0 + ct * 16 + cl) * ldk + kh;
    short8v bf[16];
#pragma unroll
    for (int kk = 0; kk < 16; ++kk) bf[kk] = *(const short8v*)(bp + kk * 32);
#pragma unroll
    for (int kk = 0; kk < 16; ++kk)
      acc[ct] = __builtin_amdgcn_mfma_f32_16x16x32_bf16(af[kk], bf[kk], acc[ct], 0, 0, 0);
  }
}

__global__ __launch_bounds__(512, 2)
void gru_scan_kernel(const float* __restrict__ h0init,
                     const float* __restrict__ pre,        // [MM][1536] u|r|c
                     const __hip_bfloat16* __restrict__ WH0, // [1536][512] u|r|c h-parts
                     const __hip_bfloat16* __restrict__ WT1, // [1536][1024] u|r|c full
                     const float* __restrict__ bu0, const float* __restrict__ br0,
                     const float* __restrict__ bc0,
                     const float* __restrict__ bu1, const float* __restrict__ br1,
                     const float* __restrict__ bc1,
                     __hip_bfloat16* __restrict__ H1b,     // [MM][512] t-major
                     float* __restrict__ fstate)           // [2][BB][512]
{
  __shared__ float h0f[16 * 512];                  // 32 KB
  __shared__ float h1f[16 * 512];                  // 32 KB
  __shared__ __hip_bfloat16 Ab[2][16 * 512];       // 32 KB (A-operand staging)
  const int tid = threadIdx.x;
  const int lane = tid & 63;
  const int w = tid >> 6;                          // 0..7
  const int r0g = blockIdx.x * 16;
  const int cl = lane & 15;
  const int qh = lane >> 4;                        // 0..3
  const int kh = qh * 8;
  const int wc0 = w * 64;

  // init: h0f = h1f = h0init rows; both Ab buffers = bf16(h0init)
  for (int i = tid; i < 16 * 512 / 4; i += 512) {
    float4 v = ((const float4*)(h0init + (size_t)r0g * 512))[i];
    ((float4*)h0f)[i] = v;
    ((float4*)h1f)[i] = v;
    __hip_bfloat16 o[4] = { __float2bfloat16(v.x), __float2bfloat16(v.y),
                            __float2bfloat16(v.z), __float2bfloat16(v.w) };
    short4v ov = *(const short4v*)o;
    ((short4v*)Ab[0])[i] = ov;
    ((short4v*)Ab[1])[i] = ov;
  }
  // register-cache biases for this wave's 4 col-tiles
  float bu0v[4], br0v[4], bc0v[4], bu1v[4], br1v[4], bc1v[4];
#pragma unroll
  for (int ct = 0; ct < 4; ++ct) {
    int c = wc0 + ct * 16 + cl;
    bu0v[ct] = bu0[c]; br0v[ct] = br0[c]; bc0v[ct] = bc0[c];
    bu1v[ct] = bu1[c]; br1v[ct] = br1[c]; bc1v[ct] = bc1[c];
  }
  __syncthreads();

  int p = 0;
  for (int t = 0; t < TT; ++t) {
    short8v af[16];
    f32x4 u0a[4] = {}, r0a[4] = {}, u1a[4] = {}, r1a[4] = {};
    // A1: layer-0 u,r h-parts (A = h0b)
    load_af(af, Ab[p], cl, kh);
    mm4(u0a, af, WH0, 512, wc0, cl, kh);
    mm4(r0a, af, WH0 + (size_t)512 * 512, 512, wc0, cl, kh);
    // A2: layer-1 u,r h-parts (A = h1b, K offset 512 within WT1 rows)
    load_af(af, Ab[p ^ 1], cl, kh);
    mm4(u1a, af, WT1 + 512, 1024, wc0, cl, kh);
    mm4(r1a, af, WT1 + (size_t)512 * 1024 + 512, 1024, wc0, cl, kh);
    __syncthreads();                               // s1

    float u0v[4][4], u1v[4][4];
    // EW1
#pragma unroll
    for (int ct = 0; ct < 4; ++ct) {
      int c = wc0 + ct * 16 + cl;
#pragma unroll
      for (int q = 0; q < 4; ++q) {
        int r = qh * 4 + q;
        size_t prow = (size_t)(t * BB + r0g + r) * 1536;
        float u0 = fsigmoid(u0a[ct][q] + bu0v[ct] + pre[prow + c]);
        float r0 = fsigmoid(r0a[ct][q] + br0v[ct] + pre[prow + 512 + c]);
        u0v[ct][q] = u0;
        Ab[p][r * 512 + c] = __float2bfloat16(r0 * h0f[r * 512 + c]);
      }
    }
    __syncthreads();                               // s2
    // B: c0 h-part (A = rh0b)
    f32x4 c0a[4] = {};
    load_af(af, Ab[p], cl, kh);
    mm4(c0a, af, WH0 + (size_t)1024 * 512, 512, wc0, cl, kh);
    // EW2: h0' -> h0f and Ab[p^1]
#pragma unroll
    for (int ct = 0; ct < 4; ++ct) {
      int c = wc0 + ct * 16 + cl;
#pragma unroll
      for (int q = 0; q < 4; ++q) {
        int r = qh * 4 + q;
        size_t prow = (size_t)(t * BB + r0g + r) * 1536;
        float c0 = ftanh(c0a[ct][q] + bc0v[ct] + pre[prow + 1024 + c]);
        float ho = h0f[r * 512 + c];
        float hn = u0v[ct][q] * ho + (1.0f - u0v[ct][q]) * c0;
        h0f[r * 512 + c] = hn;
        Ab[p ^ 1][r * 512 + c] = __float2bfloat16(hn);
      }
    }
    __syncthreads();                               // s3
    // C: layer-1 x-parts (A = h0'b)
    f32x4 c1a[4] = {};
    load_af(af, Ab[p ^ 1], cl, kh);
    mm4(u1a, af, WT1, 1024, wc0, cl, kh);
    mm4(r1a, af, WT1 + (size_t)512 * 1024, 1024, wc0, cl, kh);
    mm4(c1a, af, WT1 + (size_t)1024 * 1024, 1024, wc0, cl, kh);
    // EW3
#pragma unroll
    for (int ct = 0; ct < 4; ++ct) {
      int c = wc0 + ct * 16 + cl;
#pragma unroll
      for (int q = 0; q < 4; ++q) {
        int r = qh * 4 + q;
        float u1 = fsigmoid(u1a[ct][q] + bu1v[ct]);
        float r1 = fsigmoid(r1a[ct][q] + br1v[ct]);
        u1v[ct][q] = u1;
        Ab[p][r * 512 + c] = __float2bfloat16(r1 * h1f[r * 512 + c]);
      }
    }
    __syncthreads();                               // s4
    // D: c1 h-part (A = rh1b)
    load_af(af, Ab[p], cl, kh);
    mm4(c1a, af, WT1 + (size_t)1024 * 1024 + 512, 1024, wc0, cl, kh);
    __syncthreads();                               // s5
    // EW4: h1' -> h1f, Ab[p] (= next step's h1b), H1b[t]
#pragma unroll
    for (int ct = 0; ct < 4; ++ct) {
      int c = wc0 + ct * 16 + cl;
#pragma unroll
      for (int q = 0; q < 4; ++q) {
        int r = qh * 4 + q;
        float c1 = ftanh(c1a[ct][q] + bc1v[ct]);
        float h1o = h1f[r * 512 + c];
        float hn = u1v[ct][q] * h1o + (1.0f - u1v[ct][q]) * c1;
        h1f[r * 512 + c] = hn;
        __hip_bfloat16 hb = __float2bfloat16(hn);
        Ab[p][r * 512 + c] = hb;
        H1b[(size_t)(t * BB + r0g + r) * 512 + c] = hb;
      }
    }
    __syncthreads();                               // s6
    p ^= 1;
  }

  // final state: [h0 final][h1 final]
  for (int i = tid; i < 16 * 512; i += 512) {
    int r = i >> 9, c = i & 511;
    fstate[(size_t)(r0g + r) * 512 + c] = h0f[i];
    fstate[(size_t)BB * 512 + (size_t)(r0g + r) * 512 + c] = h1f[i];
  }
}

// ---------------------------------------------------------------------------
extern "C" void kernel_launch(void* const* d_in, const int* in_sizes, int n_in,
                              void* d_out, int out_size, void* d_ws, size_t ws_size,
                              hipStream_t stream)
{
  (void)in_sizes; (void)n_in; (void)out_size; (void)ws_size;
  const float* cnn  = (const float*)d_in[0];
  const int*   xTok = (const int*)d_in[1];
  const float* emb  = (const float*)d_in[2];
  const float* inW  = (const float*)d_in[3];
  const float* inb  = (const float*)d_in[4];
  const float* Wu0  = (const float*)d_in[5];
  const float* bu0  = (const float*)d_in[6];
  const float* Wr0  = (const float*)d_in[7];
  const float* br0  = (const float*)d_in[8];
  const float* Wc0  = (const float*)d_in[9];
  const float* bc0  = (const float*)d_in[10];
  const float* Wu1  = (const float*)d_in[11];
  const float* bu1  = (const float*)d_in[12];
  const float* Wr1  = (const float*)d_in[13];
  const float* br1  = (const float*)d_in[14];
  const float* Wc1  = (const float*)d_in[15];
  const float* bc1  = (const float*)d_in[16];
  const float* outW = (const float*)d_in[17];
  const float* outb = (const float*)d_in[18];
  float* out = (float*)d_out;

  // workspace (~25 MB)
  char* ws = (char*)d_ws;
  size_t off = 0;
  auto alloc = [&](size_t bytes) { void* p = ws + off; off += (bytes + 255) & ~(size_t)255; return p; };
  __hip_bfloat16* WoT   = (__hip_bfloat16*)alloc((size_t)VPAD * HH * 2);       // [10240][512]
  __hip_bfloat16* WXcat = (__hip_bfloat16*)alloc((size_t)3 * HH * HH * 2);     // [1536][512] x-parts
  __hip_bfloat16* WH0   = (__hip_bfloat16*)alloc((size_t)3 * HH * HH * 2);     // [1536][512] h-parts
  __hip_bfloat16* WT1   = (__hip_bfloat16*)alloc((size_t)3 * HH * 2 * HH * 2); // [1536][1024]
  __hip_bfloat16* Xe    = (__hip_bfloat16*)alloc((size_t)MM * HH * 2);
  __hip_bfloat16* H1b   = (__hip_bfloat16*)alloc((size_t)MM * HH * 2);
  float* h0s = (float*)alloc((size_t)BB * HH * 4);
  // pre-activations [MM][1536] fp32 = 25 MB live in d_out's logits region
  // (164 MB; fully consumed by the scan before the logits GEMM overwrites).
  float* pre = out;

  // 1. weight transposes -> bf16 BT layouts
  transpose_to_bf16<<<dim3(VPAD / 32, HH / 32), 256, 0, stream>>>(outW, VV, HH, VV, WoT);
  // layer-0 x-parts (rows 0..511) -> WXcat gate-major
  transpose_to_bf16<<<dim3(16, 16), 256, 0, stream>>>(Wu0, HH, HH, HH, WXcat);
  transpose_to_bf16<<<dim3(16, 16), 256, 0, stream>>>(Wr0, HH, HH, HH, WXcat + (size_t)HH * HH);
  transpose_to_bf16<<<dim3(16, 16), 256, 0, stream>>>(Wc0, HH, HH, HH, WXcat + (size_t)2 * HH * HH);
  // layer-0 h-parts (rows 512..1023) -> WH0 gate-major
  transpose_to_bf16<<<dim3(16, 16), 256, 0, stream>>>(Wu0 + (size_t)HH * HH, HH, HH, HH, WH0);
  transpose_to_bf16<<<dim3(16, 16), 256, 0, stream>>>(Wr0 + (size_t)HH * HH, HH, HH, HH, WH0 + (size_t)HH * HH);
  transpose_to_bf16<<<dim3(16, 16), 256, 0, stream>>>(Wc0 + (size_t)HH * HH, HH, HH, HH, WH0 + (size_t)2 * HH * HH);
  // layer-1 full (K=1024) -> WT1 gate-major
  transpose_to_bf16<<<dim3(16, 32), 256, 0, stream>>>(Wu1, HH, 2 * HH, HH, WT1);
  transpose_to_bf16<<<dim3(16, 32), 256, 0, stream>>>(Wr1, HH, 2 * HH, HH, WT1 + (size_t)HH * 2 * HH);
  transpose_to_bf16<<<dim3(16, 32), 256, 0, stream>>>(Wc1, HH, 2 * HH, HH, WT1 + (size_t)2 * HH * 2 * HH);

  // 2. initial hidden state
  h0_kernel<<<dim3(8, 16), 256, 0, stream>>>(cnn, inW, inb, h0s);

  // 3. embedding gather (bf16)
  gather_kernel<<<MM, 128, 0, stream>>>(xTok, emb, Xe);

  // 4. fused layer-0 x-projections for all t: pre[MM][1536] (biases added in scan)
  mfma_gemm_bt<false, false><<<dim3(12, MM / 128), 256, 0, stream>>>(Xe, WXcat, nullptr, pre, 1536);

  // 5. persistent GRU scan (one kernel, 32 steps inside)
  gru_scan_kernel<<<8, 512, 0, stream>>>(h0s, pre, WH0, WT1,
                                         bu0, br0, bc0, bu1, br1, bc1,
                                         H1b, out + (size_t)MM * VV);

  // 6. batched logits GEMM with (t,b)->(b,t) remap + bias
  mfma_gemm_bt<true, true><<<dim3(VPAD / 128, MM / 128), 256, 0, stream>>>(H1b, WoT, outb, out, VV);
}

// Round 5
// 3333.864 us; speedup vs baseline: 1.9119x; 1.9119x over previous
//
#include <hip/hip_runtime.h>
#include <hip/hip_bf16.h>

#define BB 128      // batch
#define TT 32       // seq
#define HH 512      // hidden = emb
#define VV 10000    // vocab
#define VPAD 10240  // vocab padded to 128
#define CFEAT 2048  // cnn features
#define MM 4096     // BB*TT
#define NWG 48      // scan workgroups (6 groups x 8 col-slices)

typedef __attribute__((ext_vector_type(4))) float f32x4;
typedef __attribute__((ext_vector_type(8))) short short8v;
typedef __attribute__((ext_vector_type(4))) short short4v;

__device__ __forceinline__ void gload_lds16(const void* g, void* l) {
  __builtin_amdgcn_global_load_lds(
      (const __attribute__((address_space(1))) unsigned int*)g,
      (__attribute__((address_space(3))) unsigned int*)l, 16, 0, 0);
}

__device__ __forceinline__ float fsigmoid(float x) { return 1.0f / (1.0f + __expf(-x)); }
__device__ __forceinline__ float ftanh(float x) {
  x = fminf(15.0f, fmaxf(-15.0f, x));
  float t = __expf(2.0f * x);
  return (t - 1.0f) / (t + 1.0f);
}

// ---------------------------------------------------------------------------
// Transpose fp32 [K][N] (ld ldin) -> bf16 [Npad][K], zero-pad n>=Nreal
__global__ __launch_bounds__(256)
void transpose_to_bf16(const float* __restrict__ in, int ldin, int K, int Nreal,
                       __hip_bfloat16* __restrict__ out)
{
  __shared__ float tile[32][33];
  const int tid = threadIdx.x;
  const int tx = tid & 31, ty = tid >> 5;
  const int k0 = blockIdx.y * 32;
  const int n0 = blockIdx.x * 32;
#pragma unroll
  for (int i = 0; i < 4; ++i) {
    int k = k0 + ty + i * 8;
    int n = n0 + tx;
    tile[ty + i * 8][tx] = (n < Nreal) ? in[(size_t)k * ldin + n] : 0.0f;
  }
  __syncthreads();
#pragma unroll
  for (int i = 0; i < 4; ++i) {
    int n = n0 + ty + i * 8;
    int k = k0 + tx;
    out[(size_t)n * K + k] = __float2bfloat16(tile[tx][ty + i * 8]);
  }
}

// ---------------------------------------------------------------------------
// h0 = tanh(cnn @ in_W + in_b).  grid (8,16) block 256
__global__ __launch_bounds__(256)
void h0_kernel(const float* __restrict__ cnn, const float* __restrict__ inW,
               const float* __restrict__ inb, float* __restrict__ h0)
{
  __shared__ float xT[8][CFEAT];
  const int tid = threadIdx.x;
  const int r0 = blockIdx.y * 8;
  const int j0 = blockIdx.x * 64;
  {
    const float4* src = (const float4*)(cnn + (size_t)r0 * CFEAT);
    float4* dst = (float4*)&xT[0][0];
    for (int i = tid; i < 4096; i += 256) dst[i] = src[i];
  }
  __syncthreads();
  const int jj = tid & 63, rg = tid >> 6;
  const int j = j0 + jj;
  float a0 = 0.0f, a1 = 0.0f;
  for (int k4 = 0; k4 < CFEAT; k4 += 4) {
    f32x4 x0 = *(const f32x4*)&xT[rg * 2 + 0][k4];
    f32x4 x1 = *(const f32x4*)&xT[rg * 2 + 1][k4];
#pragma unroll
    for (int kk = 0; kk < 4; ++kk) {
      float wv = inW[(size_t)(k4 + kk) * HH + j];
      a0 += x0[kk] * wv;
      a1 += x1[kk] * wv;
    }
  }
  const float bb = inb[j];
  const int row0 = r0 + rg * 2;
  h0[(size_t)(row0 + 0) * HH + j] = ftanh(a0 + bb);
  h0[(size_t)(row0 + 1) * HH + j] = ftanh(a1 + bb);
}

// ---------------------------------------------------------------------------
// Gather embedding rows -> bf16 Xe[t*128+b][512].  grid 4096, block 128
__global__ __launch_bounds__(128)
void gather_kernel(const int* __restrict__ xTok, const float* __restrict__ emb,
                   __hip_bfloat16* __restrict__ Xe)
{
  const int r = blockIdx.x;
  const int t = r >> 7, b = r & 127;
  const int tok = xTok[b * TT + t];
  float4 v = ((const float4*)(emb + (size_t)tok * HH))[threadIdx.x];
  __hip_bfloat16 o[4] = { __float2bfloat16(v.x), __float2bfloat16(v.y),
                          __float2bfloat16(v.z), __float2bfloat16(v.w) };
  *(short4v*)(Xe + (size_t)r * HH + threadIdx.x * 4) = *(const short4v*)o;
}

// ---------------------------------------------------------------------------
// bf16 MFMA GEMM, C[M][Nreal] = A[M][512] @ BT[Npad][512]^T (+ bias).
template<bool REMAP, bool HASBIAS>
__global__ __launch_bounds__(256)
void mfma_gemm_bt(const __hip_bfloat16* __restrict__ A,
                  const __hip_bfloat16* __restrict__ BT,
                  const float* __restrict__ bias,
                  float* __restrict__ C, int Nreal)
{
  constexpr int K = 512;
  __shared__ __hip_bfloat16 ldsA[128 * 32];
  __shared__ __hip_bfloat16 ldsB[128 * 32];
  const int tid = threadIdx.x;
  const int lane = tid & 63;
  const int w = tid >> 6;
  const long m0 = (long)blockIdx.y * 128;
  const long n0 = (long)blockIdx.x * 128;
  const int wr = (w >> 1) * 64, wc = (w & 1) * 64;
  const int srow = lane >> 2;
  const int skoff = (lane & 3) * 8;
  f32x4 acc[4][4] = {};

  for (int kt = 0; kt < K; kt += 32) {
    __syncthreads();
#pragma unroll
    for (int i = 0; i < 2; ++i) {
      int c = w + i * 4;
      int row = c * 16 + srow;
      gload_lds16(A + (m0 + row) * K + kt + skoff, ldsA + c * 512 + lane * 8);
      gload_lds16(BT + (n0 + row) * K + kt + skoff, ldsB + c * 512 + lane * 8);
    }
    __syncthreads();
    short8v af[4], bfv[4];
#pragma unroll
    for (int m = 0; m < 4; ++m)
      af[m] = *(const short8v*)(ldsA + (wr + m * 16 + (lane & 15)) * 32 + (lane >> 4) * 8);
#pragma unroll
    for (int n = 0; n < 4; ++n)
      bfv[n] = *(const short8v*)(ldsB + (wc + n * 16 + (lane & 15)) * 32 + (lane >> 4) * 8);
#pragma unroll
    for (int m = 0; m < 4; ++m)
#pragma unroll
      for (int n = 0; n < 4; ++n)
        acc[m][n] = __builtin_amdgcn_mfma_f32_16x16x32_bf16(af[m], bfv[n], acc[m][n], 0, 0, 0);
  }

#pragma unroll
  for (int m = 0; m < 4; ++m) {
#pragma unroll
    for (int n = 0; n < 4; ++n) {
      int col = (int)n0 + wc + n * 16 + (lane & 15);
      if (col < Nreal) {
        float bv = 0.0f;
        if constexpr (HASBIAS) bv = bias[col];
#pragma unroll
        for (int q = 0; q < 4; ++q) {
          long row = m0 + wr + m * 16 + (lane >> 4) * 4 + q;
          float v = acc[m][n][q] + bv;
          if (REMAP) {
            long t = row >> 7, b = row & 127;
            C[(b * TT + t) * (long)Nreal + col] = v;
          } else {
            C[row * (long)Nreal + col] = v;
          }
        }
      }
    }
  }
}

// ---------------------------------------------------------------------------
// Cooperative GRU scan: 48 WGs = 6 gate-groups x 8 col-slices(64 cols).
// Weights LDS-resident (loaded once, XOR-swizzled). h-state exchanged through
// global memory with agent-scope fenced grid barriers (3 per step, pipelined:
// c1's h-part of step t-1 runs inside P1(t)).
//
// Groups: 0=u0h  1=r0h  2=c0h  3=u1(x+h)  4=r1(x+h)  5=c1(x+h)
// P1: G0,G1 matmul(h0b); G5(t>0) matmul(rh1b)+finish h1(t-1)   -> u0,rh0,h1
// P2: G2 matmul(rh0b) -> h0(t)
// P3: G3,G4 matmul(h0b,h1b) -> u1,rh1;  G5 matmul(h0b) [c1 x-part, acc held]
// ---------------------------------------------------------------------------
__device__ __forceinline__ void grid_barrier(int* cnt, int target) {
  __threadfence();                      // agent fence: flush my writes
  __syncthreads();
  if (threadIdx.x == 0) {
    __hip_atomic_fetch_add(cnt, 1, __ATOMIC_ACQ_REL, __HIP_MEMORY_SCOPE_AGENT);
    while (__hip_atomic_load(cnt, __ATOMIC_ACQUIRE, __HIP_MEMORY_SCOPE_AGENT) < target)
      __builtin_amdgcn_s_sleep(1);
  }
  __syncthreads();
  __threadfence();                      // acquire: drop stale cached lines
}

// stage 64 cols x 512 K bf16 chunk into swizzled LDS ([col][K], byte^=(col&7)<<4)
__device__ __forceinline__ void stage_chunk(__hip_bfloat16* lds,
                                            const __hip_bfloat16* __restrict__ gsrc,
                                            size_t ldk)
{
  for (int i = threadIdx.x; i < 64 * 64; i += 512) {
    int col = i >> 6, slot = i & 63;
    short8v v = *(const short8v*)(gsrc + (size_t)col * ldk + slot * 8);
    int boff = (col * 1024 + slot * 16) ^ ((col & 7) << 4);
    *(short8v*)((char*)lds + boff) = v;
  }
}

// acc[ct] += A[128 rows][512] (global bf16, this wave's 16 rows) @ Wlds[64 cols][512]
__device__ __forceinline__ void mm512(f32x4 acc[4],
                                      const __hip_bfloat16* __restrict__ Ag,
                                      const __hip_bfloat16* lds, int w, int lane)
{
  const int ar = w * 16 + (lane & 15);
  const int kb = (lane >> 4) * 8;
  short8v af[16];
#pragma unroll
  for (int kk = 0; kk < 16; ++kk)
    af[kk] = *(const short8v*)(Ag + (size_t)ar * 512 + kb + kk * 32);
#pragma unroll
  for (int ct = 0; ct < 4; ++ct) {
    const int wc = ct * 16 + (lane & 15);
    const int sx = (wc & 7) << 4;
    const int sbase = wc * 1024;
#pragma unroll
    for (int kk = 0; kk < 16; ++kk) {
      short8v bf = *(const short8v*)((const char*)lds + ((sbase + (kb + kk * 32) * 2) ^ sx));
      acc[ct] = __builtin_amdgcn_mfma_f32_16x16x32_bf16(af[kk], bf, acc[ct], 0, 0, 0);
    }
  }
}

__global__ __launch_bounds__(512, 1)
void gru_scan_coop(const float* __restrict__ h0init,
                   const float* __restrict__ pre,          // [MM][1536] u|r|c
                   const __hip_bfloat16* __restrict__ WH0, // [1536][512]
                   const __hip_bfloat16* __restrict__ WT1, // [1536][1024]
                   const float* __restrict__ bu0, const float* __restrict__ br0,
                   const float* __restrict__ bc0,
                   const float* __restrict__ bu1, const float* __restrict__ br1,
                   const float* __restrict__ bc1,
                   float* __restrict__ h0f32, float* __restrict__ h1f32,
                   __hip_bfloat16* __restrict__ h0b, __hip_bfloat16* __restrict__ h1b,
                   __hip_bfloat16* __restrict__ rh0b, __hip_bfloat16* __restrict__ rh1b,
                   float* __restrict__ u0buf, float* __restrict__ u1buf,
                   __hip_bfloat16* __restrict__ H1b, float* __restrict__ fstate,
                   int* __restrict__ barcnt)
{
  __shared__ __hip_bfloat16 Wlds[2][64 * 512];     // 128 KB
  const int bidx = blockIdx.x, grp = bidx >> 3, sub = bidx & 7;
  const int tid = threadIdx.x, lane = tid & 63, w = tid >> 6;
  const int cl = lane & 15, qh = lane >> 4;
  const int col0 = sub * 64;

  // ---- one-time weight staging into LDS ----
  if (grp == 0)      stage_chunk(Wlds[0], WH0 + (size_t)(0 + col0) * 512, 512);
  else if (grp == 1) stage_chunk(Wlds[0], WH0 + (size_t)(512 + col0) * 512, 512);
  else if (grp == 2) stage_chunk(Wlds[0], WH0 + (size_t)(1024 + col0) * 512, 512);
  else if (grp == 3) {
    stage_chunk(Wlds[0], WT1 + (size_t)(0 + col0) * 1024, 1024);
    stage_chunk(Wlds[1], WT1 + (size_t)(0 + col0) * 1024 + 512, 1024);
  } else if (grp == 4) {
    stage_chunk(Wlds[0], WT1 + (size_t)(512 + col0) * 1024, 1024);
    stage_chunk(Wlds[1], WT1 + (size_t)(512 + col0) * 1024 + 512, 1024);
  } else {
    stage_chunk(Wlds[0], WT1 + (size_t)(1024 + col0) * 1024, 1024);
    stage_chunk(Wlds[1], WT1 + (size_t)(1024 + col0) * 1024 + 512, 1024);
  }

  // ---- init h state (G0's 8 blocks: rows sub*16..sub*16+16) ----
  if (grp == 0) {
    const int r0g = sub * 16;
    for (int i = tid; i < 16 * 512 / 4; i += 512) {
      float4 v = ((const float4*)(h0init + (size_t)r0g * 512))[i];
      __hip_bfloat16 o[4] = { __float2bfloat16(v.x), __float2bfloat16(v.y),
                              __float2bfloat16(v.z), __float2bfloat16(v.w) };
      short4v ov = *(const short4v*)o;
      ((float4*)(h0f32 + (size_t)r0g * 512))[i] = v;
      ((float4*)(h1f32 + (size_t)r0g * 512))[i] = v;
      ((short4v*)(h0b + (size_t)r0g * 512))[i] = ov;
      ((short4v*)(h1b + (size_t)r0g * 512))[i] = ov;
    }
  }

  // per-thread bias cache (this group's gate, 4 col-tiles)
  float bias[4];
  {
    const float* bp = (grp == 0) ? bu0 : (grp == 1) ? br0 : (grp == 2) ? bc0
                    : (grp == 3) ? bu1 : (grp == 4) ? br1 : bc1;
#pragma unroll
    for (int ct = 0; ct < 4; ++ct) bias[ct] = bp[col0 + ct * 16 + cl];
  }

  int barn = 0;
  grid_barrier(barcnt, (++barn) * NWG);

  f32x4 acc5[4] = {};                              // G5's persistent c1 accumulator
  for (int t = 0; t < TT; ++t) {
    // ===================== P1 =====================
    if (grp <= 1) {
      f32x4 acc[4] = {};
      mm512(acc, h0b, Wlds[0], w, lane);
#pragma unroll
      for (int ct = 0; ct < 4; ++ct) {
        int c = col0 + ct * 16 + cl;
#pragma unroll
        for (int q = 0; q < 4; ++q) {
          int r = w * 16 + qh * 4 + q;
          size_t idx = (size_t)r * 512 + c;
          size_t pidx = (size_t)(t * BB + r) * 1536 + (grp == 0 ? 0 : 512) + c;
          float s = fsigmoid(acc[ct][q] + bias[ct] + pre[pidx]);
          if (grp == 0) u0buf[idx] = s;
          else          rh0b[idx] = __float2bfloat16(s * h0f32[idx]);
        }
      }
    } else if (grp == 5 && t > 0) {
      mm512(acc5, rh1b, Wlds[1], w, lane);         // c1 h-part (step t-1)
#pragma unroll
      for (int ct = 0; ct < 4; ++ct) {
        int c = col0 + ct * 16 + cl;
#pragma unroll
        for (int q = 0; q < 4; ++q) {
          int r = w * 16 + qh * 4 + q;
          size_t idx = (size_t)r * 512 + c;
          float c1 = ftanh(acc5[ct][q] + bias[ct]);
          float u1 = u1buf[idx];
          float hn = u1 * h1f32[idx] + (1.0f - u1) * c1;
          h1f32[idx] = hn;
          __hip_bfloat16 hb = __float2bfloat16(hn);
          h1b[idx] = hb;
          H1b[((size_t)(t - 1) * BB + r) * 512 + c] = hb;
        }
        acc5[ct] = (f32x4){0.0f, 0.0f, 0.0f, 0.0f};
      }
    }
    grid_barrier(barcnt, (++barn) * NWG);
    // ===================== P2 =====================
    if (grp == 2) {
      f32x4 acc[4] = {};
      mm512(acc, rh0b, Wlds[0], w, lane);
#pragma unroll
      for (int ct = 0; ct < 4; ++ct) {
        int c = col0 + ct * 16 + cl;
#pragma unroll
        for (int q = 0; q < 4; ++q) {
          int r = w * 16 + qh * 4 + q;
          size_t idx = (size_t)r * 512 + c;
          float c0 = ftanh(acc[ct][q] + bias[ct] + pre[(size_t)(t * BB + r) * 1536 + 1024 + c]);
          float u0 = u0buf[idx];
          float hn = u0 * h0f32[idx] + (1.0f - u0) * c0;
          h0f32[idx] = hn;
          h0b[idx] = __float2bfloat16(hn);
          if (t == TT - 1) fstate[idx] = hn;
        }
      }
    }
    grid_barrier(barcnt, (++barn) * NWG);
    // ===================== P3 =====================
    if (grp == 3 || grp == 4) {
      f32x4 acc[4] = {};
      mm512(acc, h0b, Wlds[0], w, lane);           // x-part (h0 of step t)
      mm512(acc, h1b, Wlds[1], w, lane);           // h-part (h1 of step t-1)
#pragma unroll
      for (int ct = 0; ct < 4; ++ct) {
        int c = col0 + ct * 16 + cl;
#pragma unroll
        for (int q = 0; q < 4; ++q) {
          int r = w * 16 + qh * 4 + q;
          size_t idx = (size_t)r * 512 + c;
          float s = fsigmoid(acc[ct][q] + bias[ct]);
          if (grp == 3) u1buf[idx] = s;
          else          rh1b[idx] = __float2bfloat16(s * h1f32[idx]);
        }
      }
    } else if (grp == 5) {
      mm512(acc5, h0b, Wlds[0], w, lane);          // c1 x-part (acc held to P1(t+1))
    }
    grid_barrier(barcnt, (++barn) * NWG);
  }
  // ===== final phase: c1 h-part of step 31 + h1 EW =====
  if (grp == 5) {
    mm512(acc5, rh1b, Wlds[1], w, lane);
#pragma unroll
    for (int ct = 0; ct < 4; ++ct) {
      int c = col0 + ct * 16 + cl;
#pragma unroll
      for (int q = 0; q < 4; ++q) {
        int r = w * 16 + qh * 4 + q;
        size_t idx = (size_t)r * 512 + c;
        float c1 = ftanh(acc5[ct][q] + bias[ct]);
        float u1 = u1buf[idx];
        float hn = u1 * h1f32[idx] + (1.0f - u1) * c1;
        H1b[((size_t)(TT - 1) * BB + r) * 512 + c] = __float2bfloat16(hn);
        fstate[(size_t)BB * 512 + idx] = hn;       // final h1
      }
    }
  }
}

// ---------------------------------------------------------------------------
extern "C" void kernel_launch(void* const* d_in, const int* in_sizes, int n_in,
                              void* d_out, int out_size, void* d_ws, size_t ws_size,
                              hipStream_t stream)
{
  (void)in_sizes; (void)n_in; (void)out_size; (void)ws_size;
  const float* cnn  = (const float*)d_in[0];
  const int*   xTok = (const int*)d_in[1];
  const float* emb  = (const float*)d_in[2];
  const float* inW  = (const float*)d_in[3];
  const float* inb  = (const float*)d_in[4];
  const float* Wu0  = (const float*)d_in[5];
  const float* bu0  = (const float*)d_in[6];
  const float* Wr0  = (const float*)d_in[7];
  const float* br0  = (const float*)d_in[8];
  const float* Wc0  = (const float*)d_in[9];
  const float* bc0  = (const float*)d_in[10];
  const float* Wu1  = (const float*)d_in[11];
  const float* bu1  = (const float*)d_in[12];
  const float* Wr1  = (const float*)d_in[13];
  const float* br1  = (const float*)d_in[14];
  const float* Wc1  = (const float*)d_in[15];
  const float* bc1  = (const float*)d_in[16];
  const float* outW = (const float*)d_in[17];
  const float* outb = (const float*)d_in[18];
  float* out = (float*)d_out;

  // workspace (~27 MB)
  char* ws = (char*)d_ws;
  size_t off = 0;
  auto alloc = [&](size_t bytes) { void* p = ws + off; off += (bytes + 255) & ~(size_t)255; return p; };
  __hip_bfloat16* WoT   = (__hip_bfloat16*)alloc((size_t)VPAD * HH * 2);
  __hip_bfloat16* WXcat = (__hip_bfloat16*)alloc((size_t)3 * HH * HH * 2);      // [1536][512] x-parts
  __hip_bfloat16* WH0   = (__hip_bfloat16*)alloc((size_t)3 * HH * HH * 2);      // [1536][512] h-parts
  __hip_bfloat16* WT1   = (__hip_bfloat16*)alloc((size_t)3 * HH * 2 * HH * 2);  // [1536][1024]
  __hip_bfloat16* Xe    = (__hip_bfloat16*)alloc((size_t)MM * HH * 2);
  __hip_bfloat16* H1b   = (__hip_bfloat16*)alloc((size_t)MM * HH * 2);
  float* h0s   = (float*)alloc((size_t)BB * HH * 4);
  float* h0f32 = (float*)alloc((size_t)BB * HH * 4);
  float* h1f32 = (float*)alloc((size_t)BB * HH * 4);
  __hip_bfloat16* h0b  = (__hip_bfloat16*)alloc((size_t)BB * HH * 2);
  __hip_bfloat16* h1b  = (__hip_bfloat16*)alloc((size_t)BB * HH * 2);
  __hip_bfloat16* rh0b = (__hip_bfloat16*)alloc((size_t)BB * HH * 2);
  __hip_bfloat16* rh1b = (__hip_bfloat16*)alloc((size_t)BB * HH * 2);
  float* u0buf = (float*)alloc((size_t)BB * HH * 4);
  float* u1buf = (float*)alloc((size_t)BB * HH * 4);
  int* barcnt  = (int*)alloc(256);
  // pre-activations [MM][1536] fp32 = 25 MB live in d_out's logits region
  // (164 MB; fully consumed by the scan before the logits GEMM overwrites).
  float* pre = out;

  // 1. weight transposes -> bf16 BT layouts
  transpose_to_bf16<<<dim3(VPAD / 32, HH / 32), 256, 0, stream>>>(outW, VV, HH, VV, WoT);
  transpose_to_bf16<<<dim3(16, 16), 256, 0, stream>>>(Wu0, HH, HH, HH, WXcat);
  transpose_to_bf16<<<dim3(16, 16), 256, 0, stream>>>(Wr0, HH, HH, HH, WXcat + (size_t)HH * HH);
  transpose_to_bf16<<<dim3(16, 16), 256, 0, stream>>>(Wc0, HH, HH, HH, WXcat + (size_t)2 * HH * HH);
  transpose_to_bf16<<<dim3(16, 16), 256, 0, stream>>>(Wu0 + (size_t)HH * HH, HH, HH, HH, WH0);
  transpose_to_bf16<<<dim3(16, 16), 256, 0, stream>>>(Wr0 + (size_t)HH * HH, HH, HH, HH, WH0 + (size_t)HH * HH);
  transpose_to_bf16<<<dim3(16, 16), 256, 0, stream>>>(Wc0 + (size_t)HH * HH, HH, HH, HH, WH0 + (size_t)2 * HH * HH);
  transpose_to_bf16<<<dim3(16, 32), 256, 0, stream>>>(Wu1, HH, 2 * HH, HH, WT1);
  transpose_to_bf16<<<dim3(16, 32), 256, 0, stream>>>(Wr1, HH, 2 * HH, HH, WT1 + (size_t)HH * 2 * HH);
  transpose_to_bf16<<<dim3(16, 32), 256, 0, stream>>>(Wc1, HH, 2 * HH, HH, WT1 + (size_t)2 * HH * 2 * HH);

  // 2. initial hidden state
  h0_kernel<<<dim3(8, 16), 256, 0, stream>>>(cnn, inW, inb, h0s);

  // 3. embedding gather (bf16)
  gather_kernel<<<MM, 128, 0, stream>>>(xTok, emb, Xe);

  // 4. fused layer-0 x-projections for all t: pre[MM][1536]
  mfma_gemm_bt<false, false><<<dim3(12, MM / 128), 256, 0, stream>>>(Xe, WXcat, nullptr, pre, 1536);

  // 5. cooperative persistent GRU scan
  hipMemsetAsync(barcnt, 0, 256, stream);
  gru_scan_coop<<<NWG, 512, 0, stream>>>(h0s, pre, WH0, WT1,
                                         bu0, br0, bc0, bu1, br1, bc1,
                                         h0f32, h1f32, h0b, h1b, rh0b, rh1b,
                                         u0buf, u1buf,
                                         H1b, out + (size_t)MM * VV, barcnt);

  // 6. batched logits GEMM with (t,b)->(b,t) remap + bias
  mfma_gemm_bt<true, true><<<dim3(VPAD / 128, MM / 128), 256, 0, stream>>>(H1b, WoT, outb, out, VV);
}